// Round 7
// baseline (798.166 us; speedup 1.0000x reference)
//
#include <hip/hip_runtime.h>
#include <hip/hip_cooperative_groups.h>

// LightGCN 3-stage propagation — round 14: fused cooperative spmm with
// AGENT-SCOPE ATOMIC state exchange (fix r13's stale cross-XCD reads) +
// launch-failure fallback to the verified r11 3-dispatch path.
//
// Evidence trail (abridged):
//  r8: 261us. r10: main-loop VALU shaving -> ~0 (fixed cost dominates).
//  r11: quarter-per-row, 4 rows/wave, no reduction tail: 247.7us
//      (~37us/stage). Per-row overhead amortization is the lever.
//  r12: oct+perm REGRESSED (FETCH +34%, L2 locality loss). Reverted.
//  r13: fused cooperative spmm FAILED correctness: absmax 468 ~ fp8 max
//      448 -> stale fp8 state read across stages. Plain loads + threadfence
//      around grid.sync do NOT give cross-XCD visibility on coarse-grained
//      memory (per-XCD L2 non-coherent; poison/dirty lines served stale).
//  r14: state ping-pong accesses -> __hip_atomic_load/store at agent scope
//      (sc-flagged, coherent via Infinity Cache). col/meta/emb0/out stay
//      cached. Fallback: if hipLaunchCooperativeKernel errors, memcpy
//      emb0->acc and run the r11 spmm_fine x3 (verified-correct path).

namespace cg = cooperative_groups;

constexpr int DIM = 64;
constexpr int ROWS_PER_BKT = 256;
constexpr int BKT_CAP = 11264;      // raw max ~8.7k + pad up to 256*7 -> 10.5k
constexpr int CHUNK = 4096;
constexpr int SCAN_N = 512;
constexpr int NCHUNK = 7;           // row-group chunks per wave (unrolled)

using f32x2 = __attribute__((ext_vector_type(2))) float;

__device__ inline unsigned int pk_fp8_4(float a, float b, float c, float d) {
    int v = __builtin_amdgcn_cvt_pk_fp8_f32(a, b, 0, false);
    v = __builtin_amdgcn_cvt_pk_fp8_f32(c, d, v, true);
    return (unsigned int)v;
}

__device__ inline f32x2 pk_add(f32x2 a, f32x2 b) {
    f32x2 d;
    asm("v_pk_add_f32 %0, %1, %2" : "=v"(d) : "v"(a), "v"(b));
    return d;
}

// Block-aggregated coarse scatter into 391 row-buckets (512 threads,
// 8 edges/thread). Ranks relative to cursor[]==0 (memset).
__global__ __launch_bounds__(512) void scatter_agg(
        const int4* __restrict__ row4, const int4* __restrict__ col4,
        int* __restrict__ cursor, unsigned int* __restrict__ ebuf,
        int num_edges, int nb) {
    __shared__ unsigned int cnt[SCAN_N];
    __shared__ unsigned int orig[SCAN_N];
    __shared__ unsigned int bbase[SCAN_N];
    __shared__ unsigned int wsum[8];
    __shared__ unsigned int stage[CHUNK];
    __shared__ unsigned int dsts[CHUNK];
    const int t = threadIdx.x;

    cnt[t] = 0;
    __syncthreads();

    unsigned int pk[8];
    unsigned short bk[8], rk[8];
    const int base4 = blockIdx.x * (CHUNK / 4);
#pragma unroll
    for (int k = 0; k < 2; ++k) {
        int e4 = base4 + k * 512 + t;            // num_edges % 4 == 0
        if (e4 * 4 < num_edges) {
            int4 rr = row4[e4];
            int4 cc = col4[e4];
            int rs[4] = {rr.x, rr.y, rr.z, rr.w};
            int cs[4] = {cc.x, cc.y, cc.z, cc.w};
#pragma unroll
            for (int m = 0; m < 4; ++m) {
                int b = rs[m] >> 8;
                unsigned int rank = atomicAdd(&cnt[b], 1u);
                pk[k * 4 + m] = ((unsigned)(rs[m] & 255) << 17) | (unsigned)cs[m];
                bk[k * 4 + m] = (unsigned short)b;
                rk[k * 4 + m] = (unsigned short)rank;
            }
        } else {
#pragma unroll
            for (int m = 0; m < 4; ++m) bk[k * 4 + m] = 0xFFFFu;
        }
    }
    __syncthreads();

    // wave-level inclusive scan of cnt[] (2 barriers total)
    unsigned int myv = cnt[t];
    orig[t] = myv;
    unsigned int v = myv;
#pragma unroll
    for (int off = 1; off < 64; off <<= 1) {
        unsigned int nv = __shfl_up(v, off);
        if ((t & 63) >= off) v += nv;
    }
    if ((t & 63) == 63) wsum[t >> 6] = v;
    // per-bucket global base: independent of the scan, issue now
    if (t < nb && myv > 0)
        bbase[t] = (unsigned int)(t * BKT_CAP +
                                  atomicAdd(&cursor[t], (int)myv));
    __syncthreads();
    {
        unsigned int addv = 0;
        const int wid = t >> 6;
#pragma unroll
        for (int w = 0; w < 7; ++w)
            if (w < wid) addv += wsum[w];
        cnt[t] = v + addv;                       // inclusive scan result
    }
    __syncthreads();

#pragma unroll
    for (int k = 0; k < 8; ++k) {
        if (bk[k] != 0xFFFFu) {
            int b = bk[k];
            unsigned int ofs = (cnt[b] - orig[b]) + rk[k];
            stage[ofs] = pk[k];
            dsts[ofs] = bbase[b] + rk[k];
        }
    }
    __syncthreads();
    unsigned int total = cnt[SCAN_N - 1];
    for (unsigned int j = t; j < total; j += 512)
        ebuf[dsts[j]] = stage[j];
}

// One 512-thread block per bucket: hist -> padded scan -> permute into
// 8-aligned padded CSR (pad slots = sentinel node) -> coalesced write-out.
// col_fine stores BYTE offsets (col*64) for the fp8 state gather.
// FUSED epilogue: init acc(=emb0 copy), emb0, curA for this bucket's rows.
// (acc_out restored so the fallback path works; fused path ignores it.)
__global__ __launch_bounds__(512) void bucket_to_csr(
        const unsigned int* __restrict__ ebuf, const int* __restrict__ cursor,
        unsigned int* __restrict__ col_fine,
        int* __restrict__ row_start, int* __restrict__ row_end,
        float* __restrict__ dinv,
        const float* __restrict__ user_emb, const float* __restrict__ item_emb,
        float* __restrict__ acc_out, float* __restrict__ emb0_out,
        unsigned int* __restrict__ curA, unsigned int* __restrict__ curB,
        int n_user_elems, int n_total_elems, int n_rows, unsigned int sent) {
    __shared__ unsigned int hist[ROWS_PER_BKT];
    __shared__ unsigned int scanv[ROWS_PER_BKT];
    __shared__ unsigned int curl[ROWS_PER_BKT];
    __shared__ unsigned int wsumB[4];
    __shared__ unsigned int sorted[BKT_CAP];
    const int t = threadIdx.x;
    const int b = blockIdx.x;
    const int s = b * BKT_CAP;
    const int n = cursor[b];

    if (t < ROWS_PER_BKT) hist[t] = 0;
    __syncthreads();
    for (int j = t; j < n; j += 512)
        atomicAdd(&hist[ebuf[s + j] >> 17], 1u);
    __syncthreads();

    // wave-level inclusive scan of padded degrees (2 barriers total)
    unsigned int pdeg = 0;
    if (t < ROWS_PER_BKT) pdeg = (hist[t] + 7u) & ~7u;
    unsigned int v = pdeg;
#pragma unroll
    for (int off = 1; off < 64; off <<= 1) {
        unsigned int nv = __shfl_up(v, off);
        if ((t & 63) >= off) v += nv;
    }
    if (t < ROWS_PER_BKT && (t & 63) == 63) wsumB[t >> 6] = v;
    __syncthreads();
    if (t < ROWS_PER_BKT) {
        unsigned int addv = 0;
        const int wid = t >> 6;
#pragma unroll
        for (int w = 0; w < 3; ++w)
            if (w < wid) addv += wsumB[w];
        unsigned int incl = v + addv;
        scanv[t] = incl;
        unsigned int excl = incl - pdeg;
        curl[t] = excl;
        int r = b * ROWS_PER_BKT + t;
        if (r < n_rows) {
            unsigned int deg = hist[t];
            dinv[r] = 1.0f / sqrtf((float)(deg ? deg : 1u));
            row_start[r] = s + (int)excl;
            row_end[r]   = s + (int)(excl + pdeg);
        }
    }
    __syncthreads();
    unsigned int n_pad = scanv[ROWS_PER_BKT - 1];
    // prefill pad slots with sentinel byte offset
    const unsigned int sentb = sent << 6;
    for (unsigned int j = t; j < n_pad; j += 512) sorted[j] = sentb;
    __syncthreads();
    for (int j = t; j < n; j += 512) {
        unsigned int pk = ebuf[s + j];
        unsigned int p = atomicAdd(&curl[pk >> 17], 1u);
        sorted[p] = (pk & 0x1FFFFu) << 6;        // byte offset of fp8 row
    }
    __syncthreads();
    for (unsigned int j = t; j < n_pad; j += 512)
        col_fine[s + j] = sorted[j];

    // ---- fused init for this bucket's rows ----
    const int eb = b * ROWS_PER_BKT * DIM;
    for (int j = t * 4; j < ROWS_PER_BKT * DIM; j += 2048) {
        int i = eb + j;
        if (i >= n_total_elems) break;
        float4 v4 = (i < n_user_elems)
                       ? *(const float4*)(user_emb + i)
                       : *(const float4*)(item_emb + (i - n_user_elems));
        *(float4*)(acc_out + i)  = v4;
        *(float4*)(emb0_out + i) = v4;
        unsigned int deg = hist[j >> 6];
        float dv = 1.0f / sqrtf((float)(deg ? deg : 1u));
        curA[i >> 2] = pk_fp8_4(v4.x * dv, v4.y * dv, v4.z * dv, v4.w * dv);
    }
    // zero the sentinel row in BOTH ping-pong buffers (ws is poisoned)
    if (b == 0 && t < 16) {
        curA[(size_t)sent * 16 + t] = 0u;
        curB[(size_t)sent * 16 + t] = 0u;
    }
}

// ---------------- fused cooperative path ----------------

// One stage pass over this wave's NCHUNK row-groups (r11's verified
// quarter-per-row inner loop). State accesses are agent-scope relaxed
// atomics -> coherent across XCDs (the r13 fix).
template <bool WRITE_NEXT>
__device__ inline void stage_pass(
        float4 (&acc)[NCHUNK], const int (&sC)[NCHUNK],
        const int (&ngC)[NCHUNK], const int (&mgC)[NCHUNK],
        const float (&drC)[NCHUNK],
        const unsigned int* __restrict__ col_fine,
        const unsigned int* cur, unsigned int* nxt,
        int TW, int wg, int q, int ln, int n_rows) {
    const char* curb = (const char*)cur;
    const int ln4 = ln * 4;
#pragma unroll
    for (int c = 0; c < NCHUNK; ++c) {
        const int r = (c * TW + wg) * 4 + q;
        const int s = sC[c];
        const int ng = ngC[c];
        const int mg = mgC[c];
        f32x2 pA_lo = {0.f, 0.f}, pA_hi = {0.f, 0.f};
        f32x2 pB_lo = {0.f, 0.f}, pB_hi = {0.f, 0.f};
        for (int g = 0; g < mg; ++g) {
            if (g < ng) {                        // uniform within a quarter
                const unsigned int* cp = col_fine + s + 8 * g;
                int4 ca = *(const int4*)cp;
                int4 cb = *(const int4*)(cp + 4);
                int cc[8] = {ca.x, ca.y, ca.z, ca.w, cb.x, cb.y, cb.z, cb.w};
                unsigned int u[8];
#pragma unroll
                for (int k = 0; k < 8; ++k)
                    u[k] = __hip_atomic_load(
                        (const unsigned int*)(curb + cc[k] + ln4),
                        __ATOMIC_RELAXED, __HIP_MEMORY_SCOPE_AGENT);
#pragma unroll
                for (int k = 0; k < 8; k += 2) {
                    pA_lo = pk_add(pA_lo, __builtin_amdgcn_cvt_pk_f32_fp8(u[k], false));
                    pA_hi = pk_add(pA_hi, __builtin_amdgcn_cvt_pk_f32_fp8(u[k], true));
                    pB_lo = pk_add(pB_lo, __builtin_amdgcn_cvt_pk_f32_fp8(u[k + 1], false));
                    pB_hi = pk_add(pB_hi, __builtin_amdgcn_cvt_pk_f32_fp8(u[k + 1], true));
                }
            }
        }
        f32x2 plo = pk_add(pA_lo, pB_lo);
        f32x2 phi = pk_add(pA_hi, pB_hi);
        const float dr = drC[c];
        float t0 = dr * plo.x, t1 = dr * plo.y;
        float t2 = dr * phi.x, t3 = dr * phi.y;
        if (r < n_rows) {
            if (WRITE_NEXT)
                __hip_atomic_store(&nxt[r * 16 + ln],
                                   pk_fp8_4(dr * t0, dr * t1, dr * t2, dr * t3),
                                   __ATOMIC_RELAXED, __HIP_MEMORY_SCOPE_AGENT);
            acc[c].x += t0; acc[c].y += t1;
            acc[c].z += t2; acc[c].w += t3;
        }
    }
}

__global__ __launch_bounds__(256, 4) void spmm_fused(
        const int* __restrict__ row_start, const int* __restrict__ row_end,
        const unsigned int* __restrict__ col_fine,
        const float* __restrict__ dinv,
        unsigned int* bufA, unsigned int* bufB,
        const float* __restrict__ emb0, float* __restrict__ out,
        int n_rows) {
    cg::grid_group grid = cg::this_grid();
    const int lane = threadIdx.x & 63;
    const int q  = lane >> 4;                // quarter 0..3
    const int ln = lane & 15;                // dim group (4 dims)
    const int wg = blockIdx.x * 4 + (threadIdx.x >> 6);
    const int TW = gridDim.x * 4;            // total waves

    int   sC[NCHUNK], ngC[NCHUNK], mgC[NCHUNK];
    float drC[NCHUNK];
    float4 acc[NCHUNK];

#pragma unroll
    for (int c = 0; c < NCHUNK; ++c) {
        const int r = (c * TW + wg) * 4 + q;
        const bool valid = (r < n_rows);
        int s = 0, ng = 0;
        float dr = 0.f;
        float4 a = {0.f, 0.f, 0.f, 0.f};
        if (valid) {
            s = row_start[r];
            ng = (row_end[r] - s) >> 3;
            dr = dinv[r];
            a = *(const float4*)(emb0 + (size_t)r * DIM + 4 * ln);
        }
        int mg = ng;
        mg = max(mg, __shfl_xor(mg, 16));
        mg = max(mg, __shfl_xor(mg, 32));
        sC[c] = s; ngC[c] = ng; mgC[c] = mg; drC[c] = dr; acc[c] = a;
    }

    stage_pass<true>(acc, sC, ngC, mgC, drC, col_fine, bufA, bufB,
                     TW, wg, q, ln, n_rows);
    __threadfence();
    grid.sync();
    __threadfence();
    stage_pass<true>(acc, sC, ngC, mgC, drC, col_fine, bufB, bufA,
                     TW, wg, q, ln, n_rows);
    __threadfence();
    grid.sync();
    __threadfence();
    stage_pass<false>(acc, sC, ngC, mgC, drC, col_fine, bufA, nullptr,
                      TW, wg, q, ln, n_rows);

#pragma unroll
    for (int c = 0; c < NCHUNK; ++c) {
        const int r = (c * TW + wg) * 4 + q;
        if (r < n_rows) {
            float4 a = acc[c];
            a.x *= 0.25f; a.y *= 0.25f; a.z *= 0.25f; a.w *= 0.25f;
            *(float4*)(out + (size_t)r * DIM + 4 * ln) = a;
        }
    }
}

// ---------------- fallback path (r11, harness-verified) ----------------

__global__ __launch_bounds__(256) void spmm_fine(
        const int* __restrict__ row_start, const int* __restrict__ row_end,
        const unsigned int* __restrict__ col_fine,  // byte offsets (col*64)
        const float* __restrict__ dinv,
        const unsigned int* __restrict__ cur,   // fp8x4, pre-scaled by dinv
        unsigned int* __restrict__ next,        // fp8x4, pre-scaled by dinv
        float* __restrict__ acc,
        float scale, int write_next, int n_rows) {
    const int lane = threadIdx.x & 63;
    const int wave = (int)((blockIdx.x * blockDim.x + threadIdx.x) >> 6);
    const int q  = lane >> 4;
    const int ln = lane & 15;
    const int r = wave * 4 + q;
    const bool valid = (r < n_rows);

    int s = 0, e = 0;
    float dr = 0.f;
    float4 a = {0.f, 0.f, 0.f, 0.f};
    if (valid) {
        s = row_start[r];
        e = row_end[r];
        dr = dinv[r];
        a = *(const float4*)(acc + r * DIM + 4 * ln);
    }
    int ng = (e - s) >> 3;

    int mg = ng;
    mg = max(mg, __shfl_xor(mg, 16));
    mg = max(mg, __shfl_xor(mg, 32));

    const char* curb = (const char*)cur;
    const int ln4 = ln * 4;
    f32x2 pA_lo = {0.f, 0.f}, pA_hi = {0.f, 0.f};
    f32x2 pB_lo = {0.f, 0.f}, pB_hi = {0.f, 0.f};
    for (int g = 0; g < mg; ++g) {
        if (g < ng) {
            const unsigned int* cp = col_fine + s + 8 * g;
            int4 ca = *(const int4*)cp;
            int4 cb = *(const int4*)(cp + 4);
            int c[8] = {ca.x, ca.y, ca.z, ca.w, cb.x, cb.y, cb.z, cb.w};
            unsigned int u[8];
#pragma unroll
            for (int k = 0; k < 8; ++k)
                u[k] = *(const unsigned int*)(curb + c[k] + ln4);
#pragma unroll
            for (int k = 0; k < 8; k += 2) {
                pA_lo = pk_add(pA_lo, __builtin_amdgcn_cvt_pk_f32_fp8(u[k], false));
                pA_hi = pk_add(pA_hi, __builtin_amdgcn_cvt_pk_f32_fp8(u[k], true));
                pB_lo = pk_add(pB_lo, __builtin_amdgcn_cvt_pk_f32_fp8(u[k + 1], false));
                pB_hi = pk_add(pB_hi, __builtin_amdgcn_cvt_pk_f32_fp8(u[k + 1], true));
            }
        }
    }
    f32x2 plo = pk_add(pA_lo, pB_lo);
    f32x2 phi = pk_add(pA_hi, pB_hi);
    if (valid) {
        float t0 = dr * plo.x, t1 = dr * plo.y;
        float t2 = dr * phi.x, t3 = dr * phi.y;
        if (write_next)
            next[r * 16 + ln] = pk_fp8_4(dr * t0, dr * t1, dr * t2, dr * t3);
        a.x = (a.x + t0) * scale; a.y = (a.y + t1) * scale;
        a.z = (a.z + t2) * scale; a.w = (a.w + t3) * scale;
        *(float4*)(acc + r * DIM + 4 * ln) = a;
    }
}

extern "C" void kernel_launch(void* const* d_in, const int* in_sizes, int n_in,
                              void* d_out, int out_size, void* d_ws, size_t ws_size,
                              hipStream_t stream) {
    const float* user_emb = (const float*)d_in[0];
    const float* item_emb = (const float*)d_in[1];
    // d_in[2] = vals (recomputed as dinv[r]*dinv[c])
    const int*   row      = (const int*)d_in[3];
    const int*   col      = (const int*)d_in[4];

    const int n_user_elems  = in_sizes[0];                   // 3,200,000
    const int n_total_elems = n_user_elems + in_sizes[1];    // 6,400,000
    const int num_edges     = in_sizes[2];                   // 3,200,000
    const int n_rows        = n_total_elems / DIM;           // 100,000
    const int nb            = (n_rows + ROWS_PER_BKT - 1) / ROWS_PER_BKT; // 391
    const unsigned int sent = (unsigned int)n_rows;          // zero sentinel node

    float* out_mean = (float*)d_out;
    float* out_emb0 = out_mean + n_total_elems;

    // workspace (~49MB): curA/B fp8 (n_rows+1 rows) | ebuf | col_fine | meta
    unsigned int* curA       = (unsigned int*)d_ws;
    unsigned int* curB       = curA + (size_t)(n_rows + 1) * 16;
    unsigned int* ebuf       = curB + (size_t)(n_rows + 1) * 16;
    unsigned int* col_fine   = ebuf + (size_t)nb * BKT_CAP;
    int*          row_startp = (int*)(col_fine + (size_t)nb * BKT_CAP);
    int*          row_endp   = row_startp + n_rows;
    float*        dinv       = (float*)(row_endp + n_rows);
    int*          cursor     = (int*)(dinv + n_rows);

    hipMemsetAsync(cursor, 0, nb * sizeof(int), stream);
    scatter_agg<<<(num_edges + CHUNK - 1) / CHUNK, 512, 0, stream>>>(
        (const int4*)row, (const int4*)col, cursor, ebuf, num_edges, nb);
    bucket_to_csr<<<nb, 512, 0, stream>>>(ebuf, cursor, col_fine, row_startp,
                                          row_endp, dinv, user_emb, item_emb,
                                          out_mean, out_emb0, curA, curB,
                                          n_user_elems, n_total_elems, n_rows,
                                          sent);

    // primary: fused cooperative spmm (893 blocks, 4/CU guaranteed)
    const int FB = (n_rows + 16 * NCHUNK - 1) / (16 * NCHUNK);   // 893
    const unsigned int* cfp = col_fine;
    const float* dvp = dinv;
    const float* e0p = out_emb0;
    int nr = n_rows;
    void* kargs[] = {(void*)&row_startp, (void*)&row_endp, (void*)&cfp,
                     (void*)&dvp, (void*)&curA, (void*)&curB,
                     (void*)&e0p, (void*)&out_mean, (void*)&nr};
    hipError_t cerr = hipLaunchCooperativeKernel(
        (const void*)spmm_fused, dim3(FB), dim3(256), kargs, 0, stream);

    if (cerr != hipSuccess) {
        // fallback: verified r11 3-dispatch path (acc already = emb0 via
        // bucket_to_csr's acc_out init)
        const int spmm_blocks = (n_rows + 15) / 16;
        constexpr int STAGES = 3;
        for (int s = 0; s < STAGES; ++s) {
            int last = (s == STAGES - 1);
            float scale = last ? 1.0f / (STAGES + 1) : 1.0f;
            spmm_fine<<<spmm_blocks, 256, 0, stream>>>(row_startp, row_endp,
                                                       col_fine, dinv, curA,
                                                       curB, out_mean, scale,
                                                       !last, n_rows);
            unsigned int* t = curA; curA = curB; curB = t;
        }
    }
}

// Round 8
// 258.171 us; speedup vs baseline: 3.0916x; 3.0916x over previous
//
#include <hip/hip_runtime.h>

// LightGCN 3-stage propagation — round 15: oct-per-row SpMM with
// CONSECUTIVE rows (r12 minus perm) + single-ebuf-read CSR build.
//
// Evidence trail (abridged):
//  r8: 261us. r10: main-loop VALU shaving -> ~0 (fixed per-row cost +
//      latency chain dominate, not VALU issue).
//  r11: quarter-per-row, 4 rows/wave, no reduction tail: 247.7us
//      (~37us/stage). Per-row overhead amortization is the lever.
//  r12: oct-per-row + perm sort REGRESSED: FETCH +21MB, VALU 58->21%.
//      r15 attribution: perm scattered acc/next to random 32B slices
//      (line-waste ~ +25MB HBM, matches) — the oct SHAPE was not tested
//      clean.
//  r13: fused cooperative spmm FAILED: cross-XCD stale fp8 reads (per-XCD
//      L2 non-coherent; threadfence+grid.sync insufficient on coarse mem).
//  r14: agent-scope atomic gathers fixed correctness at 6x cost (643us,
//      VALU 6.6%, HBM 3.4% — every gather uncached). FUSION ABANDONED:
//      dispatch boundaries ARE the cheap coherence mechanism.
//  r15: (a) oct-per-row, rows = wave*8+o consecutive: VMEM instrs/edge
//      halved vs r11 (10 per 64 edges vs per 32), acc/next/out stay
//      2KB-contiguous per wave, zero reduction tail, 8x amortization;
//      100000 % 8 == 0 -> no tail. (b) bucket_to_csr reads ebuf ONCE
//      (register-cached <=22/thread, static unroll) - deletes 12.8MB
//      re-read. Falsifier: FETCH jump => oct gather shape is the problem.

constexpr int DIM = 64;
constexpr int ROWS_PER_BKT = 256;
constexpr int BKT_CAP = 11264;      // raw max ~8.7k + pad up to 256*7 -> 10.5k
constexpr int CHUNK = 4096;
constexpr int SCAN_N = 512;
constexpr int EBUF_K = 22;          // ceil(BKT_CAP/512) register-cache slots

using f32x2 = __attribute__((ext_vector_type(2))) float;

__device__ inline unsigned int pk_fp8_4(float a, float b, float c, float d) {
    int v = __builtin_amdgcn_cvt_pk_fp8_f32(a, b, 0, false);
    v = __builtin_amdgcn_cvt_pk_fp8_f32(c, d, v, true);
    return (unsigned int)v;
}

__device__ inline f32x2 pk_add(f32x2 a, f32x2 b) {
    f32x2 d;
    asm("v_pk_add_f32 %0, %1, %2" : "=v"(d) : "v"(a), "v"(b));
    return d;
}

// Block-aggregated coarse scatter into 391 row-buckets (512 threads,
// 8 edges/thread). Ranks relative to cursor[]==0 (memset).
__global__ __launch_bounds__(512) void scatter_agg(
        const int4* __restrict__ row4, const int4* __restrict__ col4,
        int* __restrict__ cursor, unsigned int* __restrict__ ebuf,
        int num_edges, int nb) {
    __shared__ unsigned int cnt[SCAN_N];
    __shared__ unsigned int orig[SCAN_N];
    __shared__ unsigned int bbase[SCAN_N];
    __shared__ unsigned int wsum[8];
    __shared__ unsigned int stage[CHUNK];
    __shared__ unsigned int dsts[CHUNK];
    const int t = threadIdx.x;

    cnt[t] = 0;
    __syncthreads();

    unsigned int pk[8];
    unsigned short bk[8], rk[8];
    const int base4 = blockIdx.x * (CHUNK / 4);
#pragma unroll
    for (int k = 0; k < 2; ++k) {
        int e4 = base4 + k * 512 + t;            // num_edges % 4 == 0
        if (e4 * 4 < num_edges) {
            int4 rr = row4[e4];
            int4 cc = col4[e4];
            int rs[4] = {rr.x, rr.y, rr.z, rr.w};
            int cs[4] = {cc.x, cc.y, cc.z, cc.w};
#pragma unroll
            for (int m = 0; m < 4; ++m) {
                int b = rs[m] >> 8;
                unsigned int rank = atomicAdd(&cnt[b], 1u);
                pk[k * 4 + m] = ((unsigned)(rs[m] & 255) << 17) | (unsigned)cs[m];
                bk[k * 4 + m] = (unsigned short)b;
                rk[k * 4 + m] = (unsigned short)rank;
            }
        } else {
#pragma unroll
            for (int m = 0; m < 4; ++m) bk[k * 4 + m] = 0xFFFFu;
        }
    }
    __syncthreads();

    // wave-level inclusive scan of cnt[] (2 barriers total)
    unsigned int myv = cnt[t];
    orig[t] = myv;
    unsigned int v = myv;
#pragma unroll
    for (int off = 1; off < 64; off <<= 1) {
        unsigned int nv = __shfl_up(v, off);
        if ((t & 63) >= off) v += nv;
    }
    if ((t & 63) == 63) wsum[t >> 6] = v;
    // per-bucket global base: independent of the scan, issue now
    if (t < nb && myv > 0)
        bbase[t] = (unsigned int)(t * BKT_CAP +
                                  atomicAdd(&cursor[t], (int)myv));
    __syncthreads();
    {
        unsigned int addv = 0;
        const int wid = t >> 6;
#pragma unroll
        for (int w = 0; w < 7; ++w)
            if (w < wid) addv += wsum[w];
        cnt[t] = v + addv;                       // inclusive scan result
    }
    __syncthreads();

#pragma unroll
    for (int k = 0; k < 8; ++k) {
        if (bk[k] != 0xFFFFu) {
            int b = bk[k];
            unsigned int ofs = (cnt[b] - orig[b]) + rk[k];
            stage[ofs] = pk[k];
            dsts[ofs] = bbase[b] + rk[k];
        }
    }
    __syncthreads();
    unsigned int total = cnt[SCAN_N - 1];
    for (unsigned int j = t; j < total; j += 512)
        ebuf[dsts[j]] = stage[j];
}

// One 512-thread block per bucket: hist -> padded scan -> permute into
// 8-aligned padded CSR (pad slots = sentinel node) -> coalesced write-out.
// col_fine stores BYTE offsets (col*64) for the fp8 state gather.
// r15: ebuf read ONCE — entries register-cached across the two phases.
// FUSED epilogue: init acc/emb0/curA for this bucket's 256 rows.
__global__ __launch_bounds__(512) void bucket_to_csr(
        const unsigned int* __restrict__ ebuf, const int* __restrict__ cursor,
        unsigned int* __restrict__ col_fine,
        int* __restrict__ row_start, int* __restrict__ row_end,
        float* __restrict__ dinv,
        const float* __restrict__ user_emb, const float* __restrict__ item_emb,
        float* __restrict__ acc_out, float* __restrict__ emb0_out,
        unsigned int* __restrict__ curA, unsigned int* __restrict__ curB,
        int n_user_elems, int n_total_elems, int n_rows, unsigned int sent) {
    __shared__ unsigned int hist[ROWS_PER_BKT];
    __shared__ unsigned int scanv[ROWS_PER_BKT];
    __shared__ unsigned int curl[ROWS_PER_BKT];
    __shared__ unsigned int wsumB[4];
    __shared__ unsigned int sorted[BKT_CAP];
    const int t = threadIdx.x;
    const int b = blockIdx.x;
    const int s = b * BKT_CAP;
    const int n = cursor[b];

    if (t < ROWS_PER_BKT) hist[t] = 0;
    __syncthreads();

    // single ebuf pass: histogram + register-cache the packed entries
    unsigned int pkc[EBUF_K];
#pragma unroll
    for (int k = 0; k < EBUF_K; ++k) {
        int j = t + k * 512;
        if (j < n) {
            unsigned int pk = ebuf[s + j];
            pkc[k] = pk;
            atomicAdd(&hist[pk >> 17], 1u);
        }
    }
    __syncthreads();

    // wave-level inclusive scan of padded degrees (2 barriers total)
    unsigned int pdeg = 0;
    if (t < ROWS_PER_BKT) pdeg = (hist[t] + 7u) & ~7u;
    unsigned int v = pdeg;
#pragma unroll
    for (int off = 1; off < 64; off <<= 1) {
        unsigned int nv = __shfl_up(v, off);
        if ((t & 63) >= off) v += nv;
    }
    if (t < ROWS_PER_BKT && (t & 63) == 63) wsumB[t >> 6] = v;
    __syncthreads();
    if (t < ROWS_PER_BKT) {
        unsigned int addv = 0;
        const int wid = t >> 6;
#pragma unroll
        for (int w = 0; w < 3; ++w)
            if (w < wid) addv += wsumB[w];
        unsigned int incl = v + addv;
        scanv[t] = incl;
        unsigned int excl = incl - pdeg;
        curl[t] = excl;
        int r = b * ROWS_PER_BKT + t;
        if (r < n_rows) {
            unsigned int deg = hist[t];
            dinv[r] = 1.0f / sqrtf((float)(deg ? deg : 1u));
            row_start[r] = s + (int)excl;
            row_end[r]   = s + (int)(excl + pdeg);
        }
    }
    __syncthreads();
    unsigned int n_pad = scanv[ROWS_PER_BKT - 1];
    // prefill pad slots with sentinel byte offset
    const unsigned int sentb = sent << 6;
    for (unsigned int j = t; j < n_pad; j += 512) sorted[j] = sentb;
    __syncthreads();
    // placement from the register cache (no second ebuf read)
#pragma unroll
    for (int k = 0; k < EBUF_K; ++k) {
        int j = t + k * 512;
        if (j < n) {
            unsigned int pk = pkc[k];
            unsigned int p = atomicAdd(&curl[pk >> 17], 1u);
            sorted[p] = (pk & 0x1FFFFu) << 6;    // byte offset of fp8 row
        }
    }
    __syncthreads();
    for (unsigned int j = t; j < n_pad; j += 512)
        col_fine[s + j] = sorted[j];

    // ---- fused init for this bucket's rows ----
    const int eb = b * ROWS_PER_BKT * DIM;
    for (int j = t * 4; j < ROWS_PER_BKT * DIM; j += 2048) {
        int i = eb + j;
        if (i >= n_total_elems) break;
        float4 v4 = (i < n_user_elems)
                       ? *(const float4*)(user_emb + i)
                       : *(const float4*)(item_emb + (i - n_user_elems));
        *(float4*)(acc_out + i)  = v4;
        *(float4*)(emb0_out + i) = v4;
        unsigned int deg = hist[j >> 6];
        float dv = 1.0f / sqrtf((float)(deg ? deg : 1u));
        curA[i >> 2] = pk_fp8_4(v4.x * dv, v4.y * dv, v4.z * dv, v4.w * dv);
    }
    // zero the sentinel row in BOTH ping-pong buffers (ws is poisoned)
    if (b == 0 && t < 16) {
        curA[(size_t)sent * 16 + t] = 0u;
        curB[(size_t)sent * 16 + t] = 0u;
    }
}

// Oct-per-row SpMM, CONSECUTIVE rows (no perm): oct o owns row wave*8+o;
// lane ln holds dims 8ln..8ln+7. Per 8-edge group: 2 int4 col loads +
// 8 dwordx2 gathers (each instr: 8 octs x one full 64B state line).
// 10 VMEM instrs per 64 edges (r11: per 32). Zero reduction tail; acc/
// next/out accesses 2KB-contiguous per wave. Pads gather the zero
// sentinel row. Divergent loop exit = exec-masked (same cost as max-ng).
__global__ __launch_bounds__(256) void spmm_fine(
        const int* __restrict__ row_start, const int* __restrict__ row_end,
        const unsigned int* __restrict__ col_fine,  // byte offsets (col*64)
        const float* __restrict__ dinv,
        const unsigned int* __restrict__ cur,   // fp8x4, pre-scaled by dinv
        unsigned int* __restrict__ next,        // fp8x4, pre-scaled by dinv
        float* __restrict__ acc,
        float scale, int write_next, int n_rows) {
    const int lane = threadIdx.x & 63;
    const int wave = (int)((blockIdx.x * blockDim.x + threadIdx.x) >> 6);
    const int o  = lane >> 3;                // oct 0..7
    const int ln = lane & 7;                 // dim slice: dims 8ln..8ln+7
    const int r = wave * 8 + o;              // consecutive rows per wave
    const bool valid = (r < n_rows);

    int s = 0, ng = 0;
    float dr = 0.f;
    float4 a0 = {0.f, 0.f, 0.f, 0.f}, a1 = {0.f, 0.f, 0.f, 0.f};
    if (valid) {
        s = row_start[r];
        ng = (row_end[r] - s) >> 3;
        dr = dinv[r];
        const float* ap = acc + r * DIM + 8 * ln;
        a0 = *(const float4*)ap;
        a1 = *(const float4*)(ap + 4);
    }

    const char* curb = (const char*)cur;
    const int ln8 = ln * 8;
    f32x2 eA = {0.f,0.f}, eB = {0.f,0.f}, eC = {0.f,0.f}, eD = {0.f,0.f};
    f32x2 oA = {0.f,0.f}, oB = {0.f,0.f}, oC = {0.f,0.f}, oD = {0.f,0.f};
    for (int g = 0; g < ng; ++g) {
        const unsigned int* cp = col_fine + s + 8 * g;
        int4 ca = *(const int4*)cp;
        int4 cb = *(const int4*)(cp + 4);
        int c[8] = {ca.x, ca.y, ca.z, ca.w, cb.x, cb.y, cb.z, cb.w};
        uint2 u[8];
#pragma unroll
        for (int k = 0; k < 8; ++k)
            u[k] = *(const uint2*)(curb + c[k] + ln8);
#pragma unroll
        for (int k = 0; k < 8; k += 2) {
            eA = pk_add(eA, __builtin_amdgcn_cvt_pk_f32_fp8(u[k].x, false));
            eB = pk_add(eB, __builtin_amdgcn_cvt_pk_f32_fp8(u[k].x, true));
            eC = pk_add(eC, __builtin_amdgcn_cvt_pk_f32_fp8(u[k].y, false));
            eD = pk_add(eD, __builtin_amdgcn_cvt_pk_f32_fp8(u[k].y, true));
            oA = pk_add(oA, __builtin_amdgcn_cvt_pk_f32_fp8(u[k + 1].x, false));
            oB = pk_add(oB, __builtin_amdgcn_cvt_pk_f32_fp8(u[k + 1].x, true));
            oC = pk_add(oC, __builtin_amdgcn_cvt_pk_f32_fp8(u[k + 1].y, false));
            oD = pk_add(oD, __builtin_amdgcn_cvt_pk_f32_fp8(u[k + 1].y, true));
        }
    }
    f32x2 pA = pk_add(eA, oA);
    f32x2 pB = pk_add(eB, oB);
    f32x2 pC = pk_add(eC, oC);
    f32x2 pD = pk_add(eD, oD);
    if (valid) {
        float t0 = dr * pA.x, t1 = dr * pA.y;
        float t2 = dr * pB.x, t3 = dr * pB.y;
        float t4 = dr * pC.x, t5 = dr * pC.y;
        float t6 = dr * pD.x, t7 = dr * pD.y;
        if (write_next) {
            uint2 w;
            w.x = pk_fp8_4(dr * t0, dr * t1, dr * t2, dr * t3);
            w.y = pk_fp8_4(dr * t4, dr * t5, dr * t6, dr * t7);
            *(uint2*)(next + r * 16 + 2 * ln) = w;
        }
        a0.x = (a0.x + t0) * scale; a0.y = (a0.y + t1) * scale;
        a0.z = (a0.z + t2) * scale; a0.w = (a0.w + t3) * scale;
        a1.x = (a1.x + t4) * scale; a1.y = (a1.y + t5) * scale;
        a1.z = (a1.z + t6) * scale; a1.w = (a1.w + t7) * scale;
        float* ap = acc + r * DIM + 8 * ln;
        *(float4*)ap       = a0;
        *(float4*)(ap + 4) = a1;
    }
}

extern "C" void kernel_launch(void* const* d_in, const int* in_sizes, int n_in,
                              void* d_out, int out_size, void* d_ws, size_t ws_size,
                              hipStream_t stream) {
    const float* user_emb = (const float*)d_in[0];
    const float* item_emb = (const float*)d_in[1];
    // d_in[2] = vals (recomputed as dinv[r]*dinv[c])
    const int*   row      = (const int*)d_in[3];
    const int*   col      = (const int*)d_in[4];

    const int n_user_elems  = in_sizes[0];                   // 3,200,000
    const int n_total_elems = n_user_elems + in_sizes[1];    // 6,400,000
    const int num_edges     = in_sizes[2];                   // 3,200,000
    const int n_rows        = n_total_elems / DIM;           // 100,000
    const int nb            = (n_rows + ROWS_PER_BKT - 1) / ROWS_PER_BKT; // 391
    const unsigned int sent = (unsigned int)n_rows;          // zero sentinel node

    float* out_mean = (float*)d_out;
    float* out_emb0 = out_mean + n_total_elems;

    // workspace (~49MB): curA/B fp8 (n_rows+1 rows) | ebuf | col_fine | meta
    unsigned int* curA       = (unsigned int*)d_ws;
    unsigned int* curB       = curA + (size_t)(n_rows + 1) * 16;
    unsigned int* ebuf       = curB + (size_t)(n_rows + 1) * 16;
    unsigned int* col_fine   = ebuf + (size_t)nb * BKT_CAP;
    int*          row_startp = (int*)(col_fine + (size_t)nb * BKT_CAP);
    int*          row_endp   = row_startp + n_rows;
    float*        dinv       = (float*)(row_endp + n_rows);
    int*          cursor     = (int*)(dinv + n_rows);

    hipMemsetAsync(cursor, 0, nb * sizeof(int), stream);
    scatter_agg<<<(num_edges + CHUNK - 1) / CHUNK, 512, 0, stream>>>(
        (const int4*)row, (const int4*)col, cursor, ebuf, num_edges, nb);
    bucket_to_csr<<<nb, 512, 0, stream>>>(ebuf, cursor, col_fine, row_startp,
                                          row_endp, dinv, user_emb, item_emb,
                                          out_mean, out_emb0, curA, curB,
                                          n_user_elems, n_total_elems, n_rows,
                                          sent);

    // 8 rows per wave -> 32 rows per 256-thread block
    const int spmm_blocks = (n_rows + 31) / 32;              // 3125
    constexpr int STAGES = 3;
    for (int s = 0; s < STAGES; ++s) {
        int last = (s == STAGES - 1);
        float scale = last ? 1.0f / (STAGES + 1) : 1.0f;
        spmm_fine<<<spmm_blocks, 256, 0, stream>>>(row_startp, row_endp,
                                                   col_fine, dinv, curA, curB,
                                                   out_mean, scale, !last,
                                                   n_rows);
        unsigned int* t = curA; curA = curB; curB = t;
    }
}

// Round 10
// 237.531 us; speedup vs baseline: 3.3603x; 1.0869x over previous
//
#include <hip/hip_runtime.h>
#include <hip/hip_fp16.h>

// LightGCN 3-stage propagation — round 17: r16 sidecar design with the
// epilogue guard bug fixed (every quarter writes its own row, as in r11).
//
// Evidence trail (abridged):
//  r10: main-loop VALU shaving -> ~0 (per-row fixed cost + latency chain
//      dominate, not VALU issue).
//  r11: quarter-per-row, 4 rows/wave, zero reduction tail: 247.7us
//      (~37us/stage; FETCH 61.5 + WRITE 31.25 = 93MB/stage). BEST.
//  r12/r15: oct shapes regress (with or without perm). Branch closed.
//  r13/r14: cross-dispatch fusion non-viable (XCD coherence costs 6x).
//  r16: f16 stage-output sidecars replace the 51.2MB/stage f32 acc
//      round-trip. FAILED on a transcription bug: epilogue guarded with
//      q==0 (r8 wave-per-row leftover) — in quarter-per-row EVERY quarter
//      owns row wave*4+q and must write (r11's guard is just `valid`).
//      3/4 of rows unwritten -> poison fp8 propagation (468s) + zero out.
//  r17: remove the q==0 guards (epilogue + final-stage hoisted loads).
//      Design unchanged: stages 1-2 write next fp8 + f16x4 sidecar t_k
//      (12.8MB write, no read); stage 3 reads t1,t2 (f16) + emb0, writes
//      out=0.25*(emb0+t1+t2+t3). Build drops acc init. -102MB/launch.
//      f16 error ~2e-4 vs 1e-2 threshold. t1 aliases dead ebuf.

constexpr int DIM = 64;
constexpr int ROWS_PER_BKT = 256;
constexpr int BKT_CAP = 11264;      // raw max ~8.7k + pad up to 256*7 -> 10.5k
constexpr int CHUNK = 4096;
constexpr int SCAN_N = 512;

using f32x2 = __attribute__((ext_vector_type(2))) float;

__device__ inline unsigned int pk_fp8_4(float a, float b, float c, float d) {
    int v = __builtin_amdgcn_cvt_pk_fp8_f32(a, b, 0, false);
    v = __builtin_amdgcn_cvt_pk_fp8_f32(c, d, v, true);
    return (unsigned int)v;
}

__device__ inline f32x2 pk_add(f32x2 a, f32x2 b) {
    f32x2 d;
    asm("v_pk_add_f32 %0, %1, %2" : "=v"(d) : "v"(a), "v"(b));
    return d;
}

__device__ inline unsigned int pk_f16_2(float a, float b) {
    auto h = __builtin_amdgcn_cvt_pkrtz(a, b);   // v_cvt_pkrtz_f16_f32
    return *reinterpret_cast<unsigned int*>(&h);
}

__device__ inline float2 up_f16_2(unsigned int u) {
    __half2 h = *reinterpret_cast<__half2*>(&u);
    return __half22float2(h);
}

// Block-aggregated coarse scatter into 391 row-buckets (512 threads,
// 8 edges/thread). Ranks relative to cursor[]==0 (memset).
__global__ __launch_bounds__(512) void scatter_agg(
        const int4* __restrict__ row4, const int4* __restrict__ col4,
        int* __restrict__ cursor, unsigned int* __restrict__ ebuf,
        int num_edges, int nb) {
    __shared__ unsigned int cnt[SCAN_N];
    __shared__ unsigned int orig[SCAN_N];
    __shared__ unsigned int bbase[SCAN_N];
    __shared__ unsigned int wsum[8];
    __shared__ unsigned int stage[CHUNK];
    __shared__ unsigned int dsts[CHUNK];
    const int t = threadIdx.x;

    cnt[t] = 0;
    __syncthreads();

    unsigned int pk[8];
    unsigned short bk[8], rk[8];
    const int base4 = blockIdx.x * (CHUNK / 4);
#pragma unroll
    for (int k = 0; k < 2; ++k) {
        int e4 = base4 + k * 512 + t;            // num_edges % 4 == 0
        if (e4 * 4 < num_edges) {
            int4 rr = row4[e4];
            int4 cc = col4[e4];
            int rs[4] = {rr.x, rr.y, rr.z, rr.w};
            int cs[4] = {cc.x, cc.y, cc.z, cc.w};
#pragma unroll
            for (int m = 0; m < 4; ++m) {
                int b = rs[m] >> 8;
                unsigned int rank = atomicAdd(&cnt[b], 1u);
                pk[k * 4 + m] = ((unsigned)(rs[m] & 255) << 17) | (unsigned)cs[m];
                bk[k * 4 + m] = (unsigned short)b;
                rk[k * 4 + m] = (unsigned short)rank;
            }
        } else {
#pragma unroll
            for (int m = 0; m < 4; ++m) bk[k * 4 + m] = 0xFFFFu;
        }
    }
    __syncthreads();

    // wave-level inclusive scan of cnt[] (2 barriers total)
    unsigned int myv = cnt[t];
    orig[t] = myv;
    unsigned int v = myv;
#pragma unroll
    for (int off = 1; off < 64; off <<= 1) {
        unsigned int nv = __shfl_up(v, off);
        if ((t & 63) >= off) v += nv;
    }
    if ((t & 63) == 63) wsum[t >> 6] = v;
    // per-bucket global base: independent of the scan, issue now
    if (t < nb && myv > 0)
        bbase[t] = (unsigned int)(t * BKT_CAP +
                                  atomicAdd(&cursor[t], (int)myv));
    __syncthreads();
    {
        unsigned int addv = 0;
        const int wid = t >> 6;
#pragma unroll
        for (int w = 0; w < 7; ++w)
            if (w < wid) addv += wsum[w];
        cnt[t] = v + addv;                       // inclusive scan result
    }
    __syncthreads();

#pragma unroll
    for (int k = 0; k < 8; ++k) {
        if (bk[k] != 0xFFFFu) {
            int b = bk[k];
            unsigned int ofs = (cnt[b] - orig[b]) + rk[k];
            stage[ofs] = pk[k];
            dsts[ofs] = bbase[b] + rk[k];
        }
    }
    __syncthreads();
    unsigned int total = cnt[SCAN_N - 1];
    for (unsigned int j = t; j < total; j += 512)
        ebuf[dsts[j]] = stage[j];
}

// One 512-thread block per bucket: hist -> padded scan -> permute into
// 8-aligned padded CSR (pad slots = sentinel node) -> coalesced write-out.
// col_fine stores BYTE offsets (col*64) for the fp8 state gather.
// FUSED epilogue: init emb0/curA for this bucket's rows (acc init deleted
// — stage sums now flow through f16 sidecars).
__global__ __launch_bounds__(512) void bucket_to_csr(
        const unsigned int* __restrict__ ebuf, const int* __restrict__ cursor,
        unsigned int* __restrict__ col_fine,
        int* __restrict__ row_start, int* __restrict__ row_end,
        float* __restrict__ dinv,
        const float* __restrict__ user_emb, const float* __restrict__ item_emb,
        float* __restrict__ emb0_out,
        unsigned int* __restrict__ curA, unsigned int* __restrict__ curB,
        int n_user_elems, int n_total_elems, int n_rows, unsigned int sent) {
    __shared__ unsigned int hist[ROWS_PER_BKT];
    __shared__ unsigned int scanv[ROWS_PER_BKT];
    __shared__ unsigned int curl[ROWS_PER_BKT];
    __shared__ unsigned int wsumB[4];
    __shared__ unsigned int sorted[BKT_CAP];
    const int t = threadIdx.x;
    const int b = blockIdx.x;
    const int s = b * BKT_CAP;
    const int n = cursor[b];

    if (t < ROWS_PER_BKT) hist[t] = 0;
    __syncthreads();
    for (int j = t; j < n; j += 512)
        atomicAdd(&hist[ebuf[s + j] >> 17], 1u);
    __syncthreads();

    // wave-level inclusive scan of padded degrees (2 barriers total)
    unsigned int pdeg = 0;
    if (t < ROWS_PER_BKT) pdeg = (hist[t] + 7u) & ~7u;
    unsigned int v = pdeg;
#pragma unroll
    for (int off = 1; off < 64; off <<= 1) {
        unsigned int nv = __shfl_up(v, off);
        if ((t & 63) >= off) v += nv;
    }
    if (t < ROWS_PER_BKT && (t & 63) == 63) wsumB[t >> 6] = v;
    __syncthreads();
    if (t < ROWS_PER_BKT) {
        unsigned int addv = 0;
        const int wid = t >> 6;
#pragma unroll
        for (int w = 0; w < 3; ++w)
            if (w < wid) addv += wsumB[w];
        unsigned int incl = v + addv;
        scanv[t] = incl;
        unsigned int excl = incl - pdeg;
        curl[t] = excl;
        int r = b * ROWS_PER_BKT + t;
        if (r < n_rows) {
            unsigned int deg = hist[t];
            dinv[r] = 1.0f / sqrtf((float)(deg ? deg : 1u));
            row_start[r] = s + (int)excl;
            row_end[r]   = s + (int)(excl + pdeg);
        }
    }
    __syncthreads();
    unsigned int n_pad = scanv[ROWS_PER_BKT - 1];
    // prefill pad slots with sentinel byte offset
    const unsigned int sentb = sent << 6;
    for (unsigned int j = t; j < n_pad; j += 512) sorted[j] = sentb;
    __syncthreads();
    for (int j = t; j < n; j += 512) {
        unsigned int pk = ebuf[s + j];
        unsigned int p = atomicAdd(&curl[pk >> 17], 1u);
        sorted[p] = (pk & 0x1FFFFu) << 6;        // byte offset of fp8 row
    }
    __syncthreads();
    for (unsigned int j = t; j < n_pad; j += 512)
        col_fine[s + j] = sorted[j];

    // ---- fused init for this bucket's rows ----
    const int eb = b * ROWS_PER_BKT * DIM;
    for (int j = t * 4; j < ROWS_PER_BKT * DIM; j += 2048) {
        int i = eb + j;
        if (i >= n_total_elems) break;
        float4 v4 = (i < n_user_elems)
                       ? *(const float4*)(user_emb + i)
                       : *(const float4*)(item_emb + (i - n_user_elems));
        *(float4*)(emb0_out + i) = v4;
        unsigned int deg = hist[j >> 6];
        float dv = 1.0f / sqrtf((float)(deg ? deg : 1u));
        curA[i >> 2] = pk_fp8_4(v4.x * dv, v4.y * dv, v4.z * dv, v4.w * dv);
    }
    // zero the sentinel row in BOTH ping-pong buffers (ws is poisoned)
    if (b == 0 && t < 16) {
        curA[(size_t)sent * 16 + t] = 0u;
        curB[(size_t)sent * 16 + t] = 0u;
    }
}

// Quarter-per-row SpMM (r11 structure, verified). Quarter q owns row
// wave*4+q; lane ln holds dims 4ln..4ln+3; EVERY quarter writes its row.
// final==0: write next fp8 + f16x4 sidecar. final==1: read t1,t2 + emb0,
// write out = 0.25*(emb0+t1+t2+t3). No f32 acc round-trip anywhere.
__global__ __launch_bounds__(256) void spmm_fine(
        const int* __restrict__ row_start, const int* __restrict__ row_end,
        const unsigned int* __restrict__ col_fine,  // byte offsets (col*64)
        const float* __restrict__ dinv,
        const unsigned int* __restrict__ cur,   // fp8x4, pre-scaled by dinv
        unsigned int* __restrict__ next,        // fp8x4, pre-scaled by dinv
        unsigned int* __restrict__ tcur,        // f16 sidecar out (final==0)
        const unsigned int* __restrict__ t1p,   // f16 sidecar in  (final==1)
        const unsigned int* __restrict__ t2p,
        const float* __restrict__ emb0,
        float* __restrict__ out,
        int final_stage, int n_rows) {
    const int lane = threadIdx.x & 63;
    const int wave = (int)((blockIdx.x * blockDim.x + threadIdx.x) >> 6);
    const int q  = lane >> 4;                // quarter 0..3
    const int ln = lane & 15;                // dim group (4 dims)
    const int r = wave * 4 + q;              // this quarter's row
    const bool valid = (r < n_rows);

    int s = 0, e = 0;
    float dr = 0.f;
    if (valid) {
        s = row_start[r];
        e = row_end[r];
        dr = dinv[r];
    }
    int ng = (e - s) >> 3;                   // 8-edge groups for this row

    // hoist final-stage streaming reads above the gather chain
    uint2 u1 = {0u, 0u}, u2 = {0u, 0u};
    float4 e0 = {0.f, 0.f, 0.f, 0.f};
    if (final_stage && valid) {
        u1 = *(const uint2*)(t1p + r * 32 + 2 * ln);
        u2 = *(const uint2*)(t2p + r * 32 + 2 * ln);
        e0 = *(const float4*)(emb0 + (size_t)r * DIM + 4 * ln);
    }

    // wave-max group count (2 shuffles, once per 4 rows)
    int mg = ng;
    mg = max(mg, __shfl_xor(mg, 16));
    mg = max(mg, __shfl_xor(mg, 32));

    const char* curb = (const char*)cur;
    const int ln4 = ln * 4;
    f32x2 pA_lo = {0.f, 0.f}, pA_hi = {0.f, 0.f};   // even k
    f32x2 pB_lo = {0.f, 0.f}, pB_hi = {0.f, 0.f};   // odd k
    for (int g = 0; g < mg; ++g) {
        if (g < ng) {                        // uniform within each quarter
            const unsigned int* cp = col_fine + s + 8 * g;
            int4 ca = *(const int4*)cp;
            int4 cb = *(const int4*)(cp + 4);
            int c[8] = {ca.x, ca.y, ca.z, ca.w, cb.x, cb.y, cb.z, cb.w};
            unsigned int u[8];
#pragma unroll
            for (int k = 0; k < 8; ++k)
                u[k] = *(const unsigned int*)(curb + c[k] + ln4);
#pragma unroll
            for (int k = 0; k < 8; k += 2) {
                pA_lo = pk_add(pA_lo, __builtin_amdgcn_cvt_pk_f32_fp8(u[k], false));
                pA_hi = pk_add(pA_hi, __builtin_amdgcn_cvt_pk_f32_fp8(u[k], true));
                pB_lo = pk_add(pB_lo, __builtin_amdgcn_cvt_pk_f32_fp8(u[k + 1], false));
                pB_hi = pk_add(pB_hi, __builtin_amdgcn_cvt_pk_f32_fp8(u[k + 1], true));
            }
        }
    }
    f32x2 plo = pk_add(pA_lo, pB_lo);
    f32x2 phi = pk_add(pA_hi, pB_hi);
    if (valid) {
        float t0 = dr * plo.x, t1 = dr * plo.y;
        float t2 = dr * phi.x, t3 = dr * phi.y;
        if (!final_stage) {
            next[r * 16 + ln] = pk_fp8_4(dr * t0, dr * t1, dr * t2, dr * t3);
            uint2 w;
            w.x = pk_f16_2(t0, t1);
            w.y = pk_f16_2(t2, t3);
            *(uint2*)(tcur + r * 32 + 2 * ln) = w;
        } else {
            float2 a1 = up_f16_2(u1.x), b1 = up_f16_2(u1.y);
            float2 a2 = up_f16_2(u2.x), b2 = up_f16_2(u2.y);
            float4 o;
            o.x = 0.25f * (e0.x + a1.x + a2.x + t0);
            o.y = 0.25f * (e0.y + a1.y + a2.y + t1);
            o.z = 0.25f * (e0.z + b1.x + b2.x + t2);
            o.w = 0.25f * (e0.w + b1.y + b2.y + t3);
            *(float4*)(out + (size_t)r * DIM + 4 * ln) = o;
        }
    }
}

extern "C" void kernel_launch(void* const* d_in, const int* in_sizes, int n_in,
                              void* d_out, int out_size, void* d_ws, size_t ws_size,
                              hipStream_t stream) {
    const float* user_emb = (const float*)d_in[0];
    const float* item_emb = (const float*)d_in[1];
    // d_in[2] = vals (recomputed as dinv[r]*dinv[c])
    const int*   row      = (const int*)d_in[3];
    const int*   col      = (const int*)d_in[4];

    const int n_user_elems  = in_sizes[0];                   // 3,200,000
    const int n_total_elems = n_user_elems + in_sizes[1];    // 6,400,000
    const int num_edges     = in_sizes[2];                   // 3,200,000
    const int n_rows        = n_total_elems / DIM;           // 100,000
    const int nb            = (n_rows + ROWS_PER_BKT - 1) / ROWS_PER_BKT; // 391
    const unsigned int sent = (unsigned int)n_rows;          // zero sentinel node

    float* out_mean = (float*)d_out;
    float* out_emb0 = out_mean + n_total_elems;

    // workspace (~62MB): curA/B fp8 | ebuf (t1 aliases it) | col_fine |
    // meta | t2. t1 reuses ebuf: dead after bucket_to_csr, written s1,
    // read s3; needs n_rows*32 uints (3.2M) <= nb*BKT_CAP (4.4M).
    unsigned int* curA       = (unsigned int*)d_ws;
    unsigned int* curB       = curA + (size_t)(n_rows + 1) * 16;
    unsigned int* ebuf       = curB + (size_t)(n_rows + 1) * 16;
    unsigned int* col_fine   = ebuf + (size_t)nb * BKT_CAP;
    int*          row_startp = (int*)(col_fine + (size_t)nb * BKT_CAP);
    int*          row_endp   = row_startp + n_rows;
    float*        dinv       = (float*)(row_endp + n_rows);
    int*          cursor     = (int*)(dinv + n_rows);
    unsigned int* t1buf      = ebuf;                         // alias (8B-aligned)
    unsigned int* t2buf      = (unsigned int*)(cursor + ((nb + 3) & ~3));

    hipMemsetAsync(cursor, 0, nb * sizeof(int), stream);
    scatter_agg<<<(num_edges + CHUNK - 1) / CHUNK, 512, 0, stream>>>(
        (const int4*)row, (const int4*)col, cursor, ebuf, num_edges, nb);
    bucket_to_csr<<<nb, 512, 0, stream>>>(ebuf, cursor, col_fine, row_startp,
                                          row_endp, dinv, user_emb, item_emb,
                                          out_emb0, curA, curB,
                                          n_user_elems, n_total_elems, n_rows,
                                          sent);

    const int spmm_blocks = (n_rows + 15) / 16;              // 4 rows/wave
    // stage 1: curA -> curB, sidecar t1
    spmm_fine<<<spmm_blocks, 256, 0, stream>>>(row_startp, row_endp, col_fine,
                                               dinv, curA, curB, t1buf,
                                               t1buf, t2buf, out_emb0,
                                               out_mean, 0, n_rows);
    // stage 2: curB -> curA, sidecar t2
    spmm_fine<<<spmm_blocks, 256, 0, stream>>>(row_startp, row_endp, col_fine,
                                               dinv, curB, curA, t2buf,
                                               t1buf, t2buf, out_emb0,
                                               out_mean, 0, n_rows);
    // stage 3: curA -> (none), combine emb0 + t1 + t2 + t3 -> out
    spmm_fine<<<spmm_blocks, 256, 0, stream>>>(row_startp, row_endp, col_fine,
                                               dinv, curA, curB, t2buf,
                                               t1buf, t2buf, out_emb0,
                                               out_mean, 1, n_rows);
}